// Round 6
// baseline (11371.651 us; speedup 1.0000x reference)
//
#include <hip/hip_runtime.h>
#include <hip/hip_bf16.h>
#include <math.h>

#define B_  32
#define T_  800
#define L_  60
#define H_  512
#define D_  1024
#define A_  512
#define FC_ 16
#define K_  101
#define C_  4000
#define TT_ 64
#define KC_ 1536   // D_ + H_

typedef short bf16x8 __attribute__((ext_vector_type(8)));
typedef float f32x4 __attribute__((ext_vector_type(4)));

__device__ __forceinline__ float fast_tanh(float x) {
  x = fminf(15.f, fmaxf(-15.f, x));
  float e = __expf(2.f * x);
  return (e - 1.f) / (e + 1.f);
}
__device__ __forceinline__ float fast_sig(float x) {
  return 1.f / (1.f + __expf(-x));
}
__device__ __forceinline__ float bflo(unsigned int u) {
  union { unsigned int i; float f; } v; v.i = u << 16; return v.f;
}
__device__ __forceinline__ float bfhi(unsigned int u) {
  union { unsigned int i; float f; } v; v.i = u & 0xffff0000u; return v.f;
}
__device__ __forceinline__ unsigned short f2bf(float f) {
  union { float f; unsigned int i; } v; v.f = f;
  unsigned int r = v.i + 0x7fff + ((v.i >> 16) & 1);
  return (unsigned short)(r >> 16);
}

// Coherent (L2-bypassing, device-visible) scalar access helpers.
__device__ __forceinline__ float cload(const float* p2) {
  return __hip_atomic_load(p2, __ATOMIC_RELAXED, __HIP_MEMORY_SCOPE_AGENT);
}
__device__ __forceinline__ void cstore(float* p2, float v) {
  __hip_atomic_store(p2, v, __ATOMIC_RELAXED, __HIP_MEMORY_SCOPE_AGENT);
}

// Hierarchical fence-free grid barrier. Round-5 single-counter version cost
// ~39us/barrier from same-line atomic contention (256 RMWs + 255 pollers on
// ONE L3 line). Here: 16 cacheline-spaced sub-counters (nb/16 RMWs each) ->
// root (16 RMWs) -> 16 per-group release words (pollers split 16 ways).
// Layout (unsigned words): sub[g]=bar[g*32], root=bar[512], rel[g]=bar[544+g*32].
__device__ __forceinline__ void grid_barrier(unsigned int* bar, int nb,
                                             unsigned int ep) {
  __syncthreads();
  if (threadIdx.x == 0) {
    asm volatile("s_waitcnt vmcnt(0)" ::: "memory");  // drain data stores
    const int g = blockIdx.x & 15;
    const unsigned int gsz = (unsigned int)(nb >> 4);
    unsigned int old = __hip_atomic_fetch_add(&bar[g * 32], 1u,
                                              __ATOMIC_RELAXED,
                                              __HIP_MEMORY_SCOPE_AGENT);
    if (old == ep * gsz - 1u) {            // group leader
      unsigned int ro = __hip_atomic_fetch_add(&bar[512], 1u,
                                               __ATOMIC_RELAXED,
                                               __HIP_MEMORY_SCOPE_AGENT);
      if (ro == ep * 16u - 1u) {           // global last -> release all groups
#pragma unroll
        for (int i = 0; i < 16; i++)
          __hip_atomic_store(&bar[544 + i * 32], ep, __ATOMIC_RELAXED,
                             __HIP_MEMORY_SCOPE_AGENT);
      }
    }
    while (__hip_atomic_load(&bar[544 + g * 32], __ATOMIC_RELAXED,
                             __HIP_MEMORY_SCOPE_AGENT) < ep) {
      __builtin_amdgcn_s_sleep(16);
    }
  }
  asm volatile("" ::: "memory");
  __syncthreads();
}

// ---------------------------------------------------------------------------
// bf16 MFMA NT GEMM: C[m,n] = sum_k A[m,k]*B[n,k] (+bias[n]).
// ---------------------------------------------------------------------------
__global__ __launch_bounds__(256) void gemm_bf16_nt(
    const unsigned short* __restrict__ Am, const unsigned short* __restrict__ Bm,
    float* __restrict__ O, unsigned short* __restrict__ Obf,
    const float* __restrict__ bias, int M, int N, int K)
{
  __shared__ unsigned short sA[128 * 40];   // stride 40 -> bank-safe
  __shared__ unsigned short sB[128 * 40];
  const int tid = threadIdx.x;
  const int mt = blockIdx.y * 128, nt = blockIdx.x * 128;
  const int wave = tid >> 6, lane = tid & 63;
  const int wm = (wave & 1) * 64, wn = (wave >> 1) * 64;
  const int qd = lane >> 4, md = lane & 15;

  f32x4 acc[4][4];
#pragma unroll
  for (int i = 0; i < 4; i++)
#pragma unroll
    for (int j = 0; j < 4; j++) acc[i][j] = (f32x4){0.f, 0.f, 0.f, 0.f};

  for (int k0 = 0; k0 < K; k0 += 32) {
#pragma unroll
    for (int p = 0; p < 2; p++) {
      int idx = tid + p * 256;            // 0..511
      int r = idx >> 2, kq = (idx & 3) * 8;
      *(uint4*)&sA[r * 40 + kq] =
          *(const uint4*)&Am[(size_t)(mt + r) * K + k0 + kq];
      uint4 bv = make_uint4(0, 0, 0, 0);
      if (nt + r < N) bv = *(const uint4*)&Bm[(size_t)(nt + r) * K + k0 + kq];
      *(uint4*)&sB[r * 40 + kq] = bv;
    }
    __syncthreads();
    bf16x8 af[4], bfr[4];
#pragma unroll
    for (int i = 0; i < 4; i++) {
      af[i]  = *(const bf16x8*)&sA[(wm + i * 16 + md) * 40 + qd * 8];
      bfr[i] = *(const bf16x8*)&sB[(wn + i * 16 + md) * 40 + qd * 8];
    }
#pragma unroll
    for (int mi = 0; mi < 4; mi++)
#pragma unroll
      for (int ni = 0; ni < 4; ni++)
        acc[mi][ni] = __builtin_amdgcn_mfma_f32_16x16x32_bf16(
            af[mi], bfr[ni], acc[mi][ni], 0, 0, 0);
    __syncthreads();
  }

#pragma unroll
  for (int mi = 0; mi < 4; mi++)
#pragma unroll
    for (int ni = 0; ni < 4; ni++) {
      int gn = nt + wn + ni * 16 + md;
      if (gn >= N) continue;
      float bv = bias ? bias[gn] : 0.f;
#pragma unroll
      for (int reg = 0; reg < 4; reg++) {
        int gm = mt + wm + mi * 16 + qd * 4 + reg;
        float v = acc[mi][ni][reg] + bv;
        if (Obf) Obf[(size_t)gm * N + gn] = f2bf(v);
        else     O[(size_t)gm * N + gn] = v;
      }
    }
}

// ---------------------------------------------------------------------------
__global__ __launch_bounds__(256) void k_cvt_f4(
    const float4* __restrict__ in, ushort4* __restrict__ out, int n4)
{
  int i = blockIdx.x * 256 + threadIdx.x;
  if (i < n4) {
    float4 v = in[i];
    ushort4 o;
    o.x = f2bf(v.x); o.y = f2bf(v.y); o.z = f2bf(v.z); o.w = f2bf(v.w);
    out[i] = o;
  }
}

// Wcell[gate][h][k], gate 0=U(W_gy|W_sy), 1..4 = I,F,Cg,O (W_gs|W_ss)
__global__ __launch_bounds__(256) void k_build_wcell(
    const float* __restrict__ W_gy, const float* __restrict__ W_sy,
    const float* __restrict__ W_gs, const float* __restrict__ W_ss,
    unsigned short* __restrict__ Wc)
{
  int idx = blockIdx.x * 256 + threadIdx.x;
  if (idx >= 5 * H_ * KC_) return;
  int row = idx / KC_;
  int k = idx - row * KC_;
  int gt = row >> 9, h = row & (H_ - 1);
  float v;
  if (gt == 0)
    v = (k < D_) ? W_gy[(size_t)h * D_ + k] : W_sy[(size_t)h * H_ + (k - D_)];
  else {
    int r = (gt - 1) * H_ + h;
    v = (k < D_) ? W_gs[(size_t)r * D_ + k] : W_ss[(size_t)r * H_ + (k - D_)];
  }
  Wc[idx] = f2bf(v);
}

// ---------------------------------------------------------------------------
// Persistent decode kernel. Grid = nb blocks (256 or 512, occupancy-checked
// on host; barrier target scales with nb so co-residency is guaranteed).
// Phase A: 416 tiles stride nb.  Phase B: 512 (b, 64-dim) units stride nb.
// Phase C: 512 split-K units stride nb.  Phase D: 32 blocks.
// ---------------------------------------------------------------------------
struct DecP {
  const unsigned short* hEbf;
  const unsigned short* hbbf;
  const unsigned short* Wcell;
  const unsigned short* W_sebf;
  const float* TY;
  const float* conv_w;
  const float* conv_b;
  const float* W_fe;
  const float* w_ee;
  const float* b_gy;
  const float* b_gs;
  const int* lengths;
  float* alpha;
  float* e;
  float* g;
  float* part;
  float* s0;
  float* s1;
  float* c;
  float* sE;
  unsigned short* u_all;
  unsigned int* bar;
  int nb;
};

__global__ __launch_bounds__(256) void k_decode(DecP p)
{
  const int bid = threadIdx.y + blockIdx.x;   // threadIdx.y==0; keeps bid in reg
  const int tid = threadIdx.x;
  const int nb = p.nb;

  // persistent (step-invariant) LDS
  __shared__ float s_wfeT[FC_ * A_];     // 32 KB
  __shared__ float s_cw[FC_ * K_];       // 6.4 KB
  __shared__ float s_wee[A_];            // 2 KB
  // per-phase scratch
  __shared__ float s_alpha[TT_ + K_ - 1];
  __shared__ float s_cf[TT_ * FC_];
  __shared__ float s_sE[A_];
  __shared__ float redA[256];
  __shared__ float redB[256];
  __shared__ float a_sh[256];
  __shared__ float sx[32 * 193];         // 24.7 KB
  __shared__ float sv[H_];

  for (int idx = tid; idx < FC_ * A_; idx += 256) {
    int f = idx >> 9, a = idx & (A_ - 1);
    s_wfeT[idx] = p.W_fe[a * FC_ + f];
  }
  for (int idx = tid; idx < FC_ * K_; idx += 256) s_cw[idx] = p.conv_w[idx];
  for (int idx = tid; idx < A_; idx += 256) s_wee[idx] = p.w_ee[idx];

  float* s_in = p.s0;
  float* s_out = p.s1;
  unsigned int ep = 0;

  for (int l = 0; l < L_; l++) {
    // ---------------- Phase A: attention energies ----------------
    for (int tile = bid; tile < 13 * B_; tile += nb) {
      const int b = tile / 13;
      const int t0 = (tile - b * 13) * TT_;
      const int len = p.lengths[b];
      if (t0 >= len) continue;      // block-uniform per tile
      for (int idx = tid; idx < TT_ + K_ - 1; idx += 256) {
        int t = t0 - (K_ / 2) + idx;
        s_alpha[idx] = (t >= 0 && t < T_) ? cload(&p.alpha[b * T_ + t]) : 0.f;
      }
      for (int idx = tid; idx < A_; idx += 256)
        s_sE[idx] = cload(&p.sE[b * A_ + idx]);
      __syncthreads();

      for (int idx = tid; idx < TT_ * FC_; idx += 256) {
        int tl = idx >> 4, f = idx & 15;
        float acc2 = p.conv_b[f];
        for (int k = 0; k < K_; k++)
          acc2 = fmaf(s_alpha[tl + k], s_cw[f * K_ + k], acc2);
        s_cf[tl * FC_ + f] = acc2;
      }
      __syncthreads();

      const int wave = tid >> 6, lane = tid & 63;
      for (int tl = wave; tl < TT_; tl += 4) {
        int t = t0 + tl;
        if (t >= len) continue;
        float cf[FC_];
#pragma unroll
        for (int f = 0; f < FC_; f++) cf[f] = s_cf[tl * FC_ + f];
        const unsigned short* hEp = p.hEbf + ((size_t)(b * T_ + t)) * A_;
        float pt = 0.f;
#pragma unroll
        for (int j = 0; j < 4; j++) {
          int a0 = j * 128 + lane * 2;
          float F0 = 0.f, F1 = 0.f;
#pragma unroll
          for (int f = 0; f < FC_; f++) {
            float2 wf = *(const float2*)&s_wfeT[f * A_ + a0];
            F0 = fmaf(wf.x, cf[f], F0);
            F1 = fmaf(wf.y, cf[f], F1);
          }
          unsigned int hp = *(const unsigned int*)&hEp[a0];
          float v0 = fast_tanh(s_sE[a0] + bflo(hp) + F0);
          float v1 = fast_tanh(s_sE[a0 + 1] + bfhi(hp) + F1);
          pt = fmaf(s_wee[a0], v0, pt);
          pt = fmaf(s_wee[a0 + 1], v1, pt);
        }
#pragma unroll
        for (int off = 32; off > 0; off >>= 1) pt += __shfl_down(pt, off);
        if (lane == 0) cstore(&p.e[b * T_ + t], pt);
      }
      __syncthreads();   // protect s_alpha/s_cf before next tile
    }
    grid_barrier(p.bar, nb, ++ep);

    // ---------------- Phase B: softmax + g (512 units of 64 dims) ----------
    for (int u = bid; u < 512; u += nb) {
      const int b = u & 31;
      const int d0 = (u >> 5) * 64;
      const int len = p.lengths[b];
      float m = -3.0e38f;
      for (int t = tid; t < len; t += 256) m = fmaxf(m, cload(&p.e[b * T_ + t]));
      redA[tid] = m;
      __syncthreads();
      for (int s2 = 128; s2 > 0; s2 >>= 1) {
        if (tid < s2) redA[tid] = fmaxf(redA[tid], redA[tid + s2]);
        __syncthreads();
      }
      m = redA[0];
      __syncthreads();
      float zs = 0.f;
      for (int t = tid; t < len; t += 256)
        zs += __expf(cload(&p.e[b * T_ + t]) - m);
      redA[tid] = zs;
      __syncthreads();
      for (int s2 = 128; s2 > 0; s2 >>= 1) {
        if (tid < s2) redA[tid] += redA[tid + s2];
        __syncthreads();
      }
      const float invZ = 1.f / redA[0];
      __syncthreads();

      const int dloc = (tid & 31) * 2, tph = tid >> 5;   // 8 t-phases x 32 lanes
      float g0 = 0.f, g1 = 0.f;
      for (int tb = 0; tb < len; tb += 256) {
        int t = tb + tid;
        float av = (t < len) ? __expf(cload(&p.e[b * T_ + t]) - m) * invZ : 0.f;
        a_sh[tid] = av;
        __syncthreads();
        if (d0 == 0 && t < len) cstore(&p.alpha[b * T_ + t], av);
        int cnt = min(256, len - tb);
        for (int tt = tph; tt < cnt; tt += 8) {
          unsigned int hp = *(const unsigned int*)
              &p.hbbf[((size_t)(b * T_ + tb + tt)) * D_ + d0 + dloc];
          float av2 = a_sh[tt];
          g0 = fmaf(av2, bflo(hp), g0);
          g1 = fmaf(av2, bfhi(hp), g1);
        }
        __syncthreads();
      }
      redA[tid] = g0;
      redB[tid] = g1;
      __syncthreads();
      if (tid < 32) {
        float r0 = 0.f, r1 = 0.f;
#pragma unroll
        for (int k2 = 0; k2 < 8; k2++) {
          r0 += redA[tid + 32 * k2];
          r1 += redB[tid + 32 * k2];
        }
        cstore(&p.g[b * D_ + d0 + 2 * tid],     r0);
        cstore(&p.g[b * D_ + d0 + 2 * tid + 1], r1);
      }
      __syncthreads();
    }
    grid_barrier(p.bar, nb, ++ep);

    // ---------------- Phase C: cell partials (split-K x8) ----------------
    for (int u = bid; u < 512; u += nb) {
      const int ks = u >> 6;
      const int xb = u & 63;
      const int k0 = ks * 192;
      for (int i = tid; i < 32 * 192; i += 256) {
        int bb = i / 192, dd = i - bb * 192;
        int k = k0 + dd;
        sx[bb * 193 + dd] = (k < D_) ? cload(&p.g[bb * D_ + k])
                                     : cload(&s_in[bb * H_ + (k - D_)]);
      }
      __syncthreads();
      const int gid = xb * 256 + tid;
      const int b = gid & 31, h = gid >> 5;
      const float* xp = &sx[b * 193];
      float acc[5] = {0.f, 0.f, 0.f, 0.f, 0.f};
      const uint4* w[5];
#pragma unroll
      for (int gt = 0; gt < 5; gt++)
        w[gt] = (const uint4*)(p.Wcell + ((size_t)(gt * H_ + h)) * KC_ + k0);
#pragma unroll 4
      for (int i = 0; i < 24; i++) {
        uint4 uu[5];
#pragma unroll
        for (int gt = 0; gt < 5; gt++) uu[gt] = w[gt][i];
        float xv[8];
#pragma unroll
        for (int e2 = 0; e2 < 8; e2++) xv[e2] = xp[i * 8 + e2];
#pragma unroll
        for (int gt = 0; gt < 5; gt++) {
          acc[gt] = fmaf(bflo(uu[gt].x), xv[0], acc[gt]);
          acc[gt] = fmaf(bfhi(uu[gt].x), xv[1], acc[gt]);
          acc[gt] = fmaf(bflo(uu[gt].y), xv[2], acc[gt]);
          acc[gt] = fmaf(bfhi(uu[gt].y), xv[3], acc[gt]);
          acc[gt] = fmaf(bflo(uu[gt].z), xv[4], acc[gt]);
          acc[gt] = fmaf(bfhi(uu[gt].z), xv[5], acc[gt]);
          acc[gt] = fmaf(bflo(uu[gt].w), xv[6], acc[gt]);
          acc[gt] = fmaf(bfhi(uu[gt].w), xv[7], acc[gt]);
        }
      }
#pragma unroll
      for (int gt = 0; gt < 5; gt++)
        cstore(&p.part[(size_t)(ks * 5 + gt) * 16384 + gid], acc[gt]);
      __syncthreads();   // protect sx before next unit
    }
    grid_barrier(p.bar, nb, ++ep);

    // ---------------- Phase D: reduce + activations + state + sE -----------
    if (bid < 32) {
      const int b = bid;
      const float* ty = p.TY + ((size_t)b * L_ + l) * (4 * H_);
      for (int h = tid; h < H_; h += 256) {
        float s5[5] = {0.f, 0.f, 0.f, 0.f, 0.f};
#pragma unroll
        for (int ks = 0; ks < 8; ks++)
#pragma unroll
          for (int gt = 0; gt < 5; gt++)
            s5[gt] += cload(&p.part[(size_t)(ks * 5 + gt) * 16384 + h * 32 + b]);
        float uv = fast_tanh(s5[0] + p.b_gy[h]);
        float iv = s5[1] + ty[h] + p.b_gs[h];
        float fv = s5[2] + ty[h + H_] + p.b_gs[h + H_];
        float cg2 = s5[3] + ty[h + 2 * H_] + p.b_gs[h + 2 * H_];
        float ov = s5[4] + ty[h + 3 * H_] + p.b_gs[h + 3 * H_];
        float cn = fast_sig(fv) * p.c[b * H_ + h] + fast_sig(iv) * fast_tanh(cg2);
        p.c[b * H_ + h] = cn;                       // block-local: plain
        float sn = fast_sig(ov) * fast_tanh(cn);
        cstore(&s_out[b * H_ + h], sn);
        sv[h] = sn;
        p.u_all[((size_t)b * L_ + l) * H_ + h] = f2bf(uv);  // read post-kernel
      }
      __syncthreads();
      for (int a = tid; a < A_; a += 256) {
        const uint4* row = (const uint4*)(p.W_sebf + (size_t)a * H_);
        float acc = 0.f;
#pragma unroll 8
        for (int i = 0; i < 64; i++) {
          uint4 ww = row[i];
          const float* xp2 = &sv[i * 8];
          acc = fmaf(bflo(ww.x), xp2[0], acc);
          acc = fmaf(bfhi(ww.x), xp2[1], acc);
          acc = fmaf(bflo(ww.y), xp2[2], acc);
          acc = fmaf(bfhi(ww.y), xp2[3], acc);
          acc = fmaf(bflo(ww.z), xp2[4], acc);
          acc = fmaf(bfhi(ww.z), xp2[5], acc);
          acc = fmaf(bflo(ww.w), xp2[6], acc);
          acc = fmaf(bfhi(ww.w), xp2[7], acc);
        }
        cstore(&p.sE[b * A_ + a], acc);
      }
    }
    grid_barrier(p.bar, nb, ++ep);

    float* tmp = s_in; s_in = s_out; s_out = tmp;
  }
}

// ---------------------------------------------------------------------------
extern "C" void kernel_launch(void* const* d_in, const int* in_sizes, int n_in,
                              void* d_out, int out_size, void* d_ws, size_t ws_size,
                              hipStream_t stream)
{
  const float* hbatch  = (const float*)d_in[0];
  const int*   lengths = (const int*)d_in[1];
  const float* targets = (const float*)d_in[2];
  const float* W_sy = (const float*)d_in[3];
  const float* W_gy = (const float*)d_in[4];
  const float* b_gy = (const float*)d_in[5];
  const float* W_yy = (const float*)d_in[6];
  const float* b_yy = (const float*)d_in[7];
  const float* W_ys = (const float*)d_in[8];
  const float* W_ss = (const float*)d_in[9];
  const float* W_gs = (const float*)d_in[10];
  const float* b_gs = (const float*)d_in[11];
  const float* W_se = (const float*)d_in[12];
  const float* W_he = (const float*)d_in[13];
  const float* W_fe = (const float*)d_in[14];
  const float* conv_w = (const float*)d_in[15];
  const float* conv_b = (const float*)d_in[16];
  const float* w_ee   = (const float*)d_in[17];
  float* out = (float*)d_out;

  char* ws = (char*)d_ws;
  size_t off = 0;
  auto alloc = [&](size_t bytes) -> void* {
    void* p = ws + off;
    off += (bytes + 255) & ~(size_t)255;
    return p;
  };
  unsigned short* hEbf   = (unsigned short*)alloc((size_t)B_ * T_ * A_ * 2);   // 26.2 MB
  unsigned short* hbbf   = (unsigned short*)alloc((size_t)B_ * T_ * D_ * 2);   // 52.4 MB
  unsigned short* Wcell  = (unsigned short*)alloc((size_t)5 * H_ * KC_ * 2);   // 7.9 MB
  unsigned short* Wyybf  = (unsigned short*)alloc((size_t)C_ * H_ * 2);        // 4.1 MB
  unsigned short* W_hebf = (unsigned short*)alloc((size_t)A_ * D_ * 2);        // 1.0 MB
  unsigned short* W_sebf = (unsigned short*)alloc((size_t)A_ * H_ * 2);        // 0.5 MB
  unsigned short* u_all  = (unsigned short*)alloc((size_t)B_ * L_ * H_ * 2);   // 2.0 MB
  float* TY    = (float*)alloc((size_t)B_ * L_ * 4 * H_ * 4);                  // 15.7 MB
  float* part  = (float*)alloc((size_t)8 * 5 * 16384 * 4);                     // 2.6 MB
  float* alpha = (float*)alloc((size_t)B_ * T_ * 4);
  float* e     = (float*)alloc((size_t)B_ * T_ * 4);
  float* g     = (float*)alloc((size_t)B_ * D_ * 4);
  float* s0    = (float*)alloc((size_t)B_ * H_ * 4);
  float* s1    = (float*)alloc((size_t)B_ * H_ * 4);
  float* c     = (float*)alloc((size_t)B_ * H_ * 4);
  float* sE    = (float*)alloc((size_t)B_ * A_ * 4);
  unsigned int* bar = (unsigned int*)alloc(8192);  // hierarchical barrier state

  // Precompute-only scratch aliases (dead after TY GEMM, stream-ordered):
  unsigned short* targetsbf = hEbf;   // 15.4 MB <= 26.2 MB
  unsigned short* W_ysbf    = hbbf;   // 16.4 MB <= 52.4 MB

  (void)hipMemsetAsync(alpha, 0, (size_t)B_ * T_ * 4, stream);
  (void)hipMemsetAsync(s0, 0, (size_t)B_ * H_ * 4, stream);
  (void)hipMemsetAsync(c, 0, (size_t)B_ * H_ * 4, stream);
  (void)hipMemsetAsync(sE, 0, (size_t)B_ * A_ * 4, stream);
  (void)hipMemsetAsync(bar, 0, 8192, stream);

  // ---- precompute ----
  {
    int n4t = B_ * L_ * C_ / 4;
    k_cvt_f4<<<(n4t + 255) / 256, 256, 0, stream>>>((const float4*)targets,
                                                    (ushort4*)targetsbf, n4t);
    int n4w = 4 * H_ * C_ / 4;
    k_cvt_f4<<<(n4w + 255) / 256, 256, 0, stream>>>((const float4*)W_ys,
                                                    (ushort4*)W_ysbf, n4w);
    gemm_bf16_nt<<<dim3(2048 / 128, 1920 / 128), 256, 0, stream>>>(
        targetsbf, W_ysbf, TY, nullptr, nullptr, 1920, 2048, 4000);

    int n4h = B_ * T_ * D_ / 4;
    k_cvt_f4<<<(n4h + 255) / 256, 256, 0, stream>>>((const float4*)hbatch,
                                                    (ushort4*)hbbf, n4h);
    int n4e = A_ * D_ / 4;
    k_cvt_f4<<<(n4e + 255) / 256, 256, 0, stream>>>((const float4*)W_he,
                                                    (ushort4*)W_hebf, n4e);
    gemm_bf16_nt<<<dim3(A_ / 128, (B_ * T_) / 128), 256, 0, stream>>>(
        hbbf, W_hebf, nullptr, hEbf, nullptr, B_ * T_, A_, D_);

    int n4y = C_ * H_ / 4;
    k_cvt_f4<<<(n4y + 255) / 256, 256, 0, stream>>>((const float4*)W_yy,
                                                    (ushort4*)Wyybf, n4y);
    int n4s = A_ * H_ / 4;
    k_cvt_f4<<<(n4s + 255) / 256, 256, 0, stream>>>((const float4*)W_se,
                                                    (ushort4*)W_sebf, n4s);
    int nw = 5 * H_ * KC_;
    k_build_wcell<<<(nw + 255) / 256, 256, 0, stream>>>(W_gy, W_sy, W_gs, W_ss,
                                                        Wcell);
  }

  // ---- persistent decode: grid sized by real occupancy (deadlock-safe) ----
  int blocksPerCU = 1;
  (void)hipOccupancyMaxActiveBlocksPerMultiprocessor(&blocksPerCU, k_decode,
                                                     256, 0);
  if (blocksPerCU < 1) blocksPerCU = 1;
  if (blocksPerCU > 2) blocksPerCU = 2;
  const int nb = 256 * blocksPerCU;   // 256 or 512; divisible by 16

  DecP p;
  p.hEbf = hEbf; p.hbbf = hbbf; p.Wcell = Wcell; p.W_sebf = W_sebf;
  p.TY = TY; p.conv_w = conv_w; p.conv_b = conv_b; p.W_fe = W_fe;
  p.w_ee = w_ee; p.b_gy = b_gy; p.b_gs = b_gs; p.lengths = lengths;
  p.alpha = alpha; p.e = e; p.g = g; p.part = part;
  p.s0 = s0; p.s1 = s1; p.c = c; p.sE = sE; p.u_all = u_all;
  p.bar = bar; p.nb = nb;
  k_decode<<<dim3(nb), dim3(256), 0, stream>>>(p);

  // ---- final: out[b,l,:] = u_all @ W_yy.T + b_yy  (bf16 MFMA) ----
  gemm_bf16_nt<<<dim3((C_ + 127) / 128, 1920 / 128), 256, 0, stream>>>(
      u_all, Wyybf, out, nullptr, b_yy, 1920, C_, H_);
}

// Round 8
// 6706.409 us; speedup vs baseline: 1.6956x; 1.6956x over previous
//
#include <hip/hip_runtime.h>
#include <hip/hip_bf16.h>
#include <math.h>

#define B_  32
#define T_  800
#define L_  60
#define H_  512
#define D_  1024
#define A_  512
#define FC_ 16
#define K_  101
#define C_  4000
#define TT_ 64
#define KC_ 1536   // D_ + H_
#define NB_ 512    // 2 blocks/CU, HW-verified co-resident (r6 profile: 24.9% occ)

typedef short bf16x8 __attribute__((ext_vector_type(8)));
typedef float f32x4 __attribute__((ext_vector_type(4)));

__device__ __forceinline__ float fast_tanh(float x) {
  x = fminf(15.f, fmaxf(-15.f, x));
  float e = __expf(2.f * x);
  return (e - 1.f) / (e + 1.f);
}
__device__ __forceinline__ float fast_sig(float x) {
  return 1.f / (1.f + __expf(-x));
}
__device__ __forceinline__ float bflo(unsigned int u) {
  union { unsigned int i; float f; } v; v.i = u << 16; return v.f;
}
__device__ __forceinline__ float bfhi(unsigned int u) {
  union { unsigned int i; float f; } v; v.i = u & 0xffff0000u; return v.f;
}
__device__ __forceinline__ unsigned short f2bf(float f) {
  union { float f; unsigned int i; } v; v.f = f;
  unsigned int r = v.i + 0x7fff + ((v.i >> 16) & 1);
  return (unsigned short)(r >> 16);
}

// Coherent (L2-bypassing, device-visible) scalar access helpers.
__device__ __forceinline__ float cload(const float* p2) {
  return __hip_atomic_load(p2, __ATOMIC_RELAXED, __HIP_MEMORY_SCOPE_AGENT);
}
__device__ __forceinline__ void cstore(float* p2, float v) {
  __hip_atomic_store(p2, v, __ATOMIC_RELAXED, __HIP_MEMORY_SCOPE_AGENT);
}

// Hierarchical fence-free grid barrier: 16 cacheline-spaced sub-counters ->
// root -> 16 per-group release words. Relaxed atomics only (coherence point);
// explicit vmcnt drain before arrival is the release.
__device__ __forceinline__ void grid_barrier(unsigned int* bar, int nb,
                                             unsigned int ep) {
  __syncthreads();
  if (threadIdx.x == 0) {
    asm volatile("s_waitcnt vmcnt(0)" ::: "memory");  // drain data stores
    const int g = blockIdx.x & 15;
    const unsigned int gsz = (unsigned int)(nb >> 4);
    unsigned int old = __hip_atomic_fetch_add(&bar[g * 32], 1u,
                                              __ATOMIC_RELAXED,
                                              __HIP_MEMORY_SCOPE_AGENT);
    if (old == ep * gsz - 1u) {            // group leader
      unsigned int ro = __hip_atomic_fetch_add(&bar[512], 1u,
                                               __ATOMIC_RELAXED,
                                               __HIP_MEMORY_SCOPE_AGENT);
      if (ro == ep * 16u - 1u) {           // global last -> release all groups
#pragma unroll
        for (int i = 0; i < 16; i++)
          __hip_atomic_store(&bar[544 + i * 32], ep, __ATOMIC_RELAXED,
                             __HIP_MEMORY_SCOPE_AGENT);
      }
    }
    while (__hip_atomic_load(&bar[544 + g * 32], __ATOMIC_RELAXED,
                             __HIP_MEMORY_SCOPE_AGENT) < ep) {
      __builtin_amdgcn_s_sleep(4);
    }
  }
  asm volatile("" ::: "memory");
  __syncthreads();
}

// ---------------------------------------------------------------------------
// bf16 MFMA NT GEMM: C[m,n] = sum_k A[m,k]*B[n,k] (+bias[n]).
// ---------------------------------------------------------------------------
__global__ __launch_bounds__(256) void gemm_bf16_nt(
    const unsigned short* __restrict__ Am, const unsigned short* __restrict__ Bm,
    float* __restrict__ O, unsigned short* __restrict__ Obf,
    const float* __restrict__ bias, int M, int N, int K)
{
  __shared__ unsigned short sA[128 * 40];   // stride 40 -> bank-safe
  __shared__ unsigned short sB[128 * 40];
  const int tid = threadIdx.x;
  const int mt = blockIdx.y * 128, nt = blockIdx.x * 128;
  const int wave = tid >> 6, lane = tid & 63;
  const int wm = (wave & 1) * 64, wn = (wave >> 1) * 64;
  const int qd = lane >> 4, md = lane & 15;

  f32x4 acc[4][4];
#pragma unroll
  for (int i = 0; i < 4; i++)
#pragma unroll
    for (int j = 0; j < 4; j++) acc[i][j] = (f32x4){0.f, 0.f, 0.f, 0.f};

  for (int k0 = 0; k0 < K; k0 += 32) {
#pragma unroll
    for (int p = 0; p < 2; p++) {
      int idx = tid + p * 256;            // 0..511
      int r = idx >> 2, kq = (idx & 3) * 8;
      *(uint4*)&sA[r * 40 + kq] =
          *(const uint4*)&Am[(size_t)(mt + r) * K + k0 + kq];
      uint4 bv = make_uint4(0, 0, 0, 0);
      if (nt + r < N) bv = *(const uint4*)&Bm[(size_t)(nt + r) * K + k0 + kq];
      *(uint4*)&sB[r * 40 + kq] = bv;
    }
    __syncthreads();
    bf16x8 af[4], bfr[4];
#pragma unroll
    for (int i = 0; i < 4; i++) {
      af[i]  = *(const bf16x8*)&sA[(wm + i * 16 + md) * 40 + qd * 8];
      bfr[i] = *(const bf16x8*)&sB[(wn + i * 16 + md) * 40 + qd * 8];
    }
#pragma unroll
    for (int mi = 0; mi < 4; mi++)
#pragma unroll
      for (int ni = 0; ni < 4; ni++)
        acc[mi][ni] = __builtin_amdgcn_mfma_f32_16x16x32_bf16(
            af[mi], bfr[ni], acc[mi][ni], 0, 0, 0);
    __syncthreads();
  }

#pragma unroll
  for (int mi = 0; mi < 4; mi++)
#pragma unroll
    for (int ni = 0; ni < 4; ni++) {
      int gn = nt + wn + ni * 16 + md;
      if (gn >= N) continue;
      float bv = bias ? bias[gn] : 0.f;
#pragma unroll
      for (int reg = 0; reg < 4; reg++) {
        int gm = mt + wm + mi * 16 + qd * 4 + reg;
        float v = acc[mi][ni][reg] + bv;
        if (Obf) Obf[(size_t)gm * N + gn] = f2bf(v);
        else     O[(size_t)gm * N + gn] = v;
      }
    }
}

// ---------------------------------------------------------------------------
__global__ __launch_bounds__(256) void k_cvt_f4(
    const float4* __restrict__ in, ushort4* __restrict__ out, int n4)
{
  int i = blockIdx.x * 256 + threadIdx.x;
  if (i < n4) {
    float4 v = in[i];
    ushort4 o;
    o.x = f2bf(v.x); o.y = f2bf(v.y); o.z = f2bf(v.z); o.w = f2bf(v.w);
    out[i] = o;
  }
}

// Wcell[gate][h][k], gate 0=U(W_gy|W_sy), 1..4 = I,F,Cg,O (W_gs|W_ss)
__global__ __launch_bounds__(256) void k_build_wcell(
    const float* __restrict__ W_gy, const float* __restrict__ W_sy,
    const float* __restrict__ W_gs, const float* __restrict__ W_ss,
    unsigned short* __restrict__ Wc)
{
  int idx = blockIdx.x * 256 + threadIdx.x;
  if (idx >= 5 * H_ * KC_) return;
  int row = idx / KC_;
  int k = idx - row * KC_;
  int gt = row >> 9, h = row & (H_ - 1);
  float v;
  if (gt == 0)
    v = (k < D_) ? W_gy[(size_t)h * D_ + k] : W_sy[(size_t)h * H_ + (k - D_)];
  else {
    int r = (gt - 1) * H_ + h;
    v = (k < D_) ? W_gs[(size_t)r * D_ + k] : W_ss[(size_t)r * H_ + (k - D_)];
  }
  Wc[idx] = f2bf(v);
}

// ---------------------------------------------------------------------------
// Persistent decode kernel. Grid = 512 blocks (2/CU, hard-coded; verified on
// HW in round-6 profile). Phase A: 416 tiles. Phase B: 512 (b, 64-dim) units.
// Phase C: 512 split-K units. Phase D: 32 blocks.
// part layout: [plane=ks*5+gt][b*512+h]  -> coalesced coherent reads in D.
// ---------------------------------------------------------------------------
struct DecP {
  const unsigned short* hEbf;
  const unsigned short* hbbf;
  const unsigned short* Wcell;
  const unsigned short* W_sebf;
  const float* TY;
  const float* conv_w;
  const float* conv_b;
  const float* W_fe;
  const float* w_ee;
  const float* b_gy;
  const float* b_gs;
  const int* lengths;
  float* alpha;
  float* e;
  float* g;
  float* part;
  float* s0;
  float* s1;
  float* c;
  float* sE;
  unsigned short* u_all;
  unsigned int* bar;
  int nb;
};

__global__ __launch_bounds__(256) void k_decode(DecP p)
{
  const int bid = blockIdx.x;
  const int tid = threadIdx.x;
  const int nb = p.nb;

  // persistent (step-invariant) LDS
  __shared__ float s_wfeT[FC_ * A_];     // 32 KB
  __shared__ float s_cw[FC_ * K_];       // 6.4 KB
  __shared__ float s_wee[A_];            // 2 KB
  // per-phase scratch
  __shared__ float s_alpha[TT_ + K_ - 1];
  __shared__ float s_cf[TT_ * FC_];      // phase A: conv feat; phase B: e-row
  __shared__ float s_sE[A_];
  __shared__ float redA[256];
  __shared__ float redB[256];
  __shared__ float a_sh[256];
  __shared__ float sx[32 * 193];         // 24.7 KB
  __shared__ float sv[H_];

  for (int idx = tid; idx < FC_ * A_; idx += 256) {
    int f = idx >> 9, a = idx & (A_ - 1);
    s_wfeT[idx] = p.W_fe[a * FC_ + f];
  }
  for (int idx = tid; idx < FC_ * K_; idx += 256) s_cw[idx] = p.conv_w[idx];
  for (int idx = tid; idx < A_; idx += 256) s_wee[idx] = p.w_ee[idx];

  float* s_in = p.s0;
  float* s_out = p.s1;
  unsigned int ep = 0;

  for (int l = 0; l < L_; l++) {
    // ---------------- Phase A: attention energies ----------------
    for (int tile = bid; tile < 13 * B_; tile += nb) {
      const int b = tile / 13;
      const int t0 = (tile - b * 13) * TT_;
      const int len = p.lengths[b];
      if (t0 >= len) continue;      // block-uniform per tile
      for (int idx = tid; idx < TT_ + K_ - 1; idx += 256) {
        int t = t0 - (K_ / 2) + idx;
        s_alpha[idx] = (t >= 0 && t < T_) ? cload(&p.alpha[b * T_ + t]) : 0.f;
      }
      for (int idx = tid; idx < A_; idx += 256)
        s_sE[idx] = cload(&p.sE[b * A_ + idx]);
      __syncthreads();

      for (int idx = tid; idx < TT_ * FC_; idx += 256) {
        int tl = idx >> 4, f = idx & 15;
        float acc2 = p.conv_b[f];
        for (int k = 0; k < K_; k++)
          acc2 = fmaf(s_alpha[tl + k], s_cw[f * K_ + k], acc2);
        s_cf[tl * FC_ + f] = acc2;
      }
      __syncthreads();

      const int wave = tid >> 6, lane = tid & 63;
      for (int tl = wave; tl < TT_; tl += 4) {
        int t = t0 + tl;
        if (t >= len) continue;
        float cf[FC_];
#pragma unroll
        for (int f = 0; f < FC_; f++) cf[f] = s_cf[tl * FC_ + f];
        const unsigned short* hEp = p.hEbf + ((size_t)(b * T_ + t)) * A_;
        float pt = 0.f;
#pragma unroll
        for (int j = 0; j < 4; j++) {
          int a0 = j * 128 + lane * 2;
          float F0 = 0.f, F1 = 0.f;
#pragma unroll
          for (int f = 0; f < FC_; f++) {
            float2 wf = *(const float2*)&s_wfeT[f * A_ + a0];
            F0 = fmaf(wf.x, cf[f], F0);
            F1 = fmaf(wf.y, cf[f], F1);
          }
          unsigned int hp = *(const unsigned int*)&hEp[a0];
          float v0 = fast_tanh(s_sE[a0] + bflo(hp) + F0);
          float v1 = fast_tanh(s_sE[a0 + 1] + bfhi(hp) + F1);
          pt = fmaf(s_wee[a0], v0, pt);
          pt = fmaf(s_wee[a0 + 1], v1, pt);
        }
#pragma unroll
        for (int off = 32; off > 0; off >>= 1) pt += __shfl_down(pt, off);
        if (lane == 0) cstore(&p.e[b * T_ + t], pt);
      }
      __syncthreads();   // protect s_alpha/s_cf before next tile
    }
    grid_barrier(p.bar, nb, ++ep);

    // ---------------- Phase B: softmax + g (512 units of 64 dims) ----------
    for (int u = bid; u < 512; u += nb) {
      const int b = u & 31;
      const int d0 = (u >> 5) * 64;
      const int len = p.lengths[b];
      // stage e row to LDS once (s_cf alias: 1024 floats >= len<=800)
      for (int t = tid; t < len; t += 256) s_cf[t] = cload(&p.e[b * T_ + t]);
      __syncthreads();
      float m = -3.0e38f;
      for (int t = tid; t < len; t += 256) m = fmaxf(m, s_cf[t]);
      redA[tid] = m;
      __syncthreads();
      for (int s2 = 128; s2 > 0; s2 >>= 1) {
        if (tid < s2) redA[tid] = fmaxf(redA[tid], redA[tid + s2]);
        __syncthreads();
      }
      m = redA[0];
      __syncthreads();
      float zs = 0.f;
      for (int t = tid; t < len; t += 256) zs += __expf(s_cf[t] - m);
      redA[tid] = zs;
      __syncthreads();
      for (int s2 = 128; s2 > 0; s2 >>= 1) {
        if (tid < s2) redA[tid] += redA[tid + s2];
        __syncthreads();
      }
      const float invZ = 1.f / redA[0];
      __syncthreads();

      const int dloc = (tid & 31) * 2, tph = tid >> 5;   // 8 t-phases x 32 lanes
      float g0 = 0.f, g1 = 0.f;
      for (int tb = 0; tb < len; tb += 256) {
        int t = tb + tid;
        float av = (t < len) ? __expf(s_cf[t] - m) * invZ : 0.f;
        a_sh[tid] = av;
        __syncthreads();
        if (d0 == 0 && t < len) cstore(&p.alpha[b * T_ + t], av);
        int cnt = min(256, len - tb);
        for (int tt = tph; tt < cnt; tt += 8) {
          unsigned int hp = *(const unsigned int*)
              &p.hbbf[((size_t)(b * T_ + tb + tt)) * D_ + d0 + dloc];
          float av2 = a_sh[tt];
          g0 = fmaf(av2, bflo(hp), g0);
          g1 = fmaf(av2, bfhi(hp), g1);
        }
        __syncthreads();
      }
      redA[tid] = g0;
      redB[tid] = g1;
      __syncthreads();
      if (tid < 32) {
        float r0 = 0.f, r1 = 0.f;
#pragma unroll
        for (int k2 = 0; k2 < 8; k2++) {
          r0 += redA[tid + 32 * k2];
          r1 += redB[tid + 32 * k2];
        }
        cstore(&p.g[b * D_ + d0 + 2 * tid],     r0);
        cstore(&p.g[b * D_ + d0 + 2 * tid + 1], r1);
      }
      __syncthreads();
    }
    grid_barrier(p.bar, nb, ++ep);

    // ---------------- Phase C: cell partials (split-K x8) ----------------
    for (int u = bid; u < 512; u += nb) {
      const int ks = u >> 6;
      const int xb = u & 63;
      const int k0 = ks * 192;
      for (int i = tid; i < 32 * 192; i += 256) {
        int bb = i / 192, dd = i - bb * 192;
        int k = k0 + dd;
        sx[bb * 193 + dd] = (k < D_) ? cload(&p.g[bb * D_ + k])
                                     : cload(&s_in[bb * H_ + (k - D_)]);
      }
      __syncthreads();
      const int gid = xb * 256 + tid;
      const int b = gid & 31, h = gid >> 5;
      const float* xp = &sx[b * 193];
      float acc[5] = {0.f, 0.f, 0.f, 0.f, 0.f};
      const uint4* w[5];
#pragma unroll
      for (int gt = 0; gt < 5; gt++)
        w[gt] = (const uint4*)(p.Wcell + ((size_t)(gt * H_ + h)) * KC_ + k0);
#pragma unroll 4
      for (int i = 0; i < 24; i++) {
        uint4 uu[5];
#pragma unroll
        for (int gt = 0; gt < 5; gt++) uu[gt] = w[gt][i];
        float xv[8];
#pragma unroll
        for (int e2 = 0; e2 < 8; e2++) xv[e2] = xp[i * 8 + e2];
#pragma unroll
        for (int gt = 0; gt < 5; gt++) {
          acc[gt] = fmaf(bflo(uu[gt].x), xv[0], acc[gt]);
          acc[gt] = fmaf(bfhi(uu[gt].x), xv[1], acc[gt]);
          acc[gt] = fmaf(bflo(uu[gt].y), xv[2], acc[gt]);
          acc[gt] = fmaf(bfhi(uu[gt].y), xv[3], acc[gt]);
          acc[gt] = fmaf(bflo(uu[gt].z), xv[4], acc[gt]);
          acc[gt] = fmaf(bfhi(uu[gt].z), xv[5], acc[gt]);
          acc[gt] = fmaf(bflo(uu[gt].w), xv[6], acc[gt]);
          acc[gt] = fmaf(bfhi(uu[gt].w), xv[7], acc[gt]);
        }
      }
      // part layout: [plane][b*512 + h] -> D reads coalesced
#pragma unroll
      for (int gt = 0; gt < 5; gt++)
        cstore(&p.part[(size_t)(ks * 5 + gt) * 16384 + b * 512 + h], acc[gt]);
      __syncthreads();   // protect sx before next unit
    }
    grid_barrier(p.bar, nb, ++ep);

    // ---------------- Phase D: reduce + activations + state + sE -----------
    if (bid < 32) {
      const int b = bid;
      const float* ty = p.TY + ((size_t)b * L_ + l) * (4 * H_);
      for (int h = tid; h < H_; h += 256) {
        float s5[5] = {0.f, 0.f, 0.f, 0.f, 0.f};
#pragma unroll
        for (int ks = 0; ks < 8; ks++)
#pragma unroll
          for (int gt = 0; gt < 5; gt++)
            s5[gt] += cload(&p.part[(size_t)(ks * 5 + gt) * 16384 + b * 512 + h]);
        float uv = fast_tanh(s5[0] + p.b_gy[h]);
        float iv = s5[1] + ty[h] + p.b_gs[h];
        float fv = s5[2] + ty[h + H_] + p.b_gs[h + H_];
        float cg2 = s5[3] + ty[h + 2 * H_] + p.b_gs[h + 2 * H_];
        float ov = s5[4] + ty[h + 3 * H_] + p.b_gs[h + 3 * H_];
        float cn = fast_sig(fv) * p.c[b * H_ + h] + fast_sig(iv) * fast_tanh(cg2);
        p.c[b * H_ + h] = cn;                       // block-local: plain
        float sn = fast_sig(ov) * fast_tanh(cn);
        cstore(&s_out[b * H_ + h], sn);
        sv[h] = sn;
        p.u_all[((size_t)b * L_ + l) * H_ + h] = f2bf(uv);  // read post-kernel
      }
      __syncthreads();
      for (int a = tid; a < A_; a += 256) {
        const uint4* row = (const uint4*)(p.W_sebf + (size_t)a * H_);
        float acc = 0.f;
#pragma unroll 8
        for (int i = 0; i < 64; i++) {
          uint4 ww = row[i];
          const float* xp2 = &sv[i * 8];
          acc = fmaf(bflo(ww.x), xp2[0], acc);
          acc = fmaf(bfhi(ww.x), xp2[1], acc);
          acc = fmaf(bflo(ww.y), xp2[2], acc);
          acc = fmaf(bfhi(ww.y), xp2[3], acc);
          acc = fmaf(bflo(ww.z), xp2[4], acc);
          acc = fmaf(bfhi(ww.z), xp2[5], acc);
          acc = fmaf(bflo(ww.w), xp2[6], acc);
          acc = fmaf(bfhi(ww.w), xp2[7], acc);
        }
        cstore(&p.sE[b * A_ + a], acc);
      }
    }
    grid_barrier(p.bar, nb, ++ep);

    float* tmp = s_in; s_in = s_out; s_out = tmp;
  }
}

// ---------------------------------------------------------------------------
extern "C" void kernel_launch(void* const* d_in, const int* in_sizes, int n_in,
                              void* d_out, int out_size, void* d_ws, size_t ws_size,
                              hipStream_t stream)
{
  const float* hbatch  = (const float*)d_in[0];
  const int*   lengths = (const int*)d_in[1];
  const float* targets = (const float*)d_in[2];
  const float* W_sy = (const float*)d_in[3];
  const float* W_gy = (const float*)d_in[4];
  const float* b_gy = (const float*)d_in[5];
  const float* W_yy = (const float*)d_in[6];
  const float* b_yy = (const float*)d_in[7];
  const float* W_ys = (const float*)d_in[8];
  const float* W_ss = (const float*)d_in[9];
  const float* W_gs = (const float*)d_in[10];
  const float* b_gs = (const float*)d_in[11];
  const float* W_se = (const float*)d_in[12];
  const float* W_he = (const float*)d_in[13];
  const float* W_fe = (const float*)d_in[14];
  const float* conv_w = (const float*)d_in[15];
  const float* conv_b = (const float*)d_in[16];
  const float* w_ee   = (const float*)d_in[17];
  float* out = (float*)d_out;

  char* ws = (char*)d_ws;
  size_t off = 0;
  auto alloc = [&](size_t bytes) -> void* {
    void* p = ws + off;
    off += (bytes + 255) & ~(size_t)255;
    return p;
  };
  unsigned short* hEbf   = (unsigned short*)alloc((size_t)B_ * T_ * A_ * 2);   // 26.2 MB
  unsigned short* hbbf   = (unsigned short*)alloc((size_t)B_ * T_ * D_ * 2);   // 52.4 MB
  unsigned short* Wcell  = (unsigned short*)alloc((size_t)5 * H_ * KC_ * 2);   // 7.9 MB
  unsigned short* Wyybf  = (unsigned short*)alloc((size_t)C_ * H_ * 2);        // 4.1 MB
  unsigned short* W_hebf = (unsigned short*)alloc((size_t)A_ * D_ * 2);        // 1.0 MB
  unsigned short* W_sebf = (unsigned short*)alloc((size_t)A_ * H_ * 2);        // 0.5 MB
  unsigned short* u_all  = (unsigned short*)alloc((size_t)B_ * L_ * H_ * 2);   // 2.0 MB
  float* TY    = (float*)alloc((size_t)B_ * L_ * 4 * H_ * 4);                  // 15.7 MB
  float* part  = (float*)alloc((size_t)8 * 5 * 16384 * 4);                     // 2.6 MB
  float* alpha = (float*)alloc((size_t)B_ * T_ * 4);
  float* e     = (float*)alloc((size_t)B_ * T_ * 4);
  float* g     = (float*)alloc((size_t)B_ * D_ * 4);
  float* s0    = (float*)alloc((size_t)B_ * H_ * 4);
  float* s1    = (float*)alloc((size_t)B_ * H_ * 4);
  float* c     = (float*)alloc((size_t)B_ * H_ * 4);
  float* sE    = (float*)alloc((size_t)B_ * A_ * 4);
  unsigned int* bar = (unsigned int*)alloc(8192);  // hierarchical barrier state

  // Precompute-only scratch aliases (dead after TY GEMM, stream-ordered):
  unsigned short* targetsbf = hEbf;   // 15.4 MB <= 26.2 MB
  unsigned short* W_ysbf    = hbbf;   // 16.4 MB <= 52.4 MB

  (void)hipMemsetAsync(alpha, 0, (size_t)B_ * T_ * 4, stream);
  (void)hipMemsetAsync(s0, 0, (size_t)B_ * H_ * 4, stream);
  (void)hipMemsetAsync(c, 0, (size_t)B_ * H_ * 4, stream);
  (void)hipMemsetAsync(sE, 0, (size_t)B_ * A_ * 4, stream);
  (void)hipMemsetAsync(bar, 0, 8192, stream);

  // ---- precompute ----
  {
    int n4t = B_ * L_ * C_ / 4;
    k_cvt_f4<<<(n4t + 255) / 256, 256, 0, stream>>>((const float4*)targets,
                                                    (ushort4*)targetsbf, n4t);
    int n4w = 4 * H_ * C_ / 4;
    k_cvt_f4<<<(n4w + 255) / 256, 256, 0, stream>>>((const float4*)W_ys,
                                                    (ushort4*)W_ysbf, n4w);
    gemm_bf16_nt<<<dim3(2048 / 128, 1920 / 128), 256, 0, stream>>>(
        targetsbf, W_ysbf, TY, nullptr, nullptr, 1920, 2048, 4000);

    int n4h = B_ * T_ * D_ / 4;
    k_cvt_f4<<<(n4h + 255) / 256, 256, 0, stream>>>((const float4*)hbatch,
                                                    (ushort4*)hbbf, n4h);
    int n4e = A_ * D_ / 4;
    k_cvt_f4<<<(n4e + 255) / 256, 256, 0, stream>>>((const float4*)W_he,
                                                    (ushort4*)W_hebf, n4e);
    gemm_bf16_nt<<<dim3(A_ / 128, (B_ * T_) / 128), 256, 0, stream>>>(
        hbbf, W_hebf, nullptr, hEbf, nullptr, B_ * T_, A_, D_);

    int n4y = C_ * H_ / 4;
    k_cvt_f4<<<(n4y + 255) / 256, 256, 0, stream>>>((const float4*)W_yy,
                                                    (ushort4*)Wyybf, n4y);
    int n4s = A_ * H_ / 4;
    k_cvt_f4<<<(n4s + 255) / 256, 256, 0, stream>>>((const float4*)W_se,
                                                    (ushort4*)W_sebf, n4s);
    int nw = 5 * H_ * KC_;
    k_build_wcell<<<(nw + 255) / 256, 256, 0, stream>>>(W_gy, W_sy, W_gs, W_ss,
                                                        Wcell);
  }

  // ---- persistent decode: 512 blocks hard-coded (2/CU, r6-verified).
  // NOTE: no occupancy query here — it fails under graph capture and was
  // silently downgrading the timed run to 256 blocks in round 6.
  DecP p;
  p.hEbf = hEbf; p.hbbf = hbbf; p.Wcell = Wcell; p.W_sebf = W_sebf;
  p.TY = TY; p.conv_w = conv_w; p.conv_b = conv_b; p.W_fe = W_fe;
  p.w_ee = w_ee; p.b_gy = b_gy; p.b_gs = b_gs; p.lengths = lengths;
  p.alpha = alpha; p.e = e; p.g = g; p.part = part;
  p.s0 = s0; p.s1 = s1; p.c = c; p.sE = sE; p.u_all = u_all;
  p.bar = bar; p.nb = NB_;
  k_decode<<<dim3(NB_), dim3(256), 0, stream>>>(p);

  // ---- final: out[b,l,:] = u_all @ W_yy.T + b_yy  (bf16 MFMA) ----
  gemm_bf16_nt<<<dim3((C_ + 127) / 128, 1920 / 128), 256, 0, stream>>>(
      u_all, Wyybf, out, nullptr, b_yy, 1920, C_, H_);
}

// Round 9
// 6605.576 us; speedup vs baseline: 1.7215x; 1.0153x over previous
//
#include <hip/hip_runtime.h>
#include <hip/hip_bf16.h>
#include <math.h>

#define B_  32
#define T_  800
#define L_  60
#define H_  512
#define D_  1024
#define A_  512
#define FC_ 16
#define K_  101
#define C_  4000
#define TT_ 50     // 16 tiles/b -> 512 tiles == nb (full block utilization in A)
#define KC_ 1536   // D_ + H_
#define NB_ 512    // 2 blocks/CU, HW-verified co-resident (r6/r8: 24.8% occ)

typedef short bf16x8 __attribute__((ext_vector_type(8)));
typedef float f32x4 __attribute__((ext_vector_type(4)));

__device__ __forceinline__ float fast_tanh(float x) {
  x = fminf(15.f, fmaxf(-15.f, x));
  float e = __expf(2.f * x);
  return (e - 1.f) / (e + 1.f);
}
__device__ __forceinline__ float fast_sig(float x) {
  return 1.f / (1.f + __expf(-x));
}
__device__ __forceinline__ float bflo(unsigned int u) {
  union { unsigned int i; float f; } v; v.i = u << 16; return v.f;
}
__device__ __forceinline__ float bfhi(unsigned int u) {
  union { unsigned int i; float f; } v; v.i = u & 0xffff0000u; return v.f;
}
__device__ __forceinline__ unsigned short f2bf(float f) {
  union { float f; unsigned int i; } v; v.f = f;
  unsigned int r = v.i + 0x7fff + ((v.i >> 16) & 1);
  return (unsigned short)(r >> 16);
}

// Coherent (L2-bypassing, device-visible) scalar access helpers.
__device__ __forceinline__ float cload(const float* p2) {
  return __hip_atomic_load(p2, __ATOMIC_RELAXED, __HIP_MEMORY_SCOPE_AGENT);
}
__device__ __forceinline__ void cstore(float* p2, float v) {
  __hip_atomic_store(p2, v, __ATOMIC_RELAXED, __HIP_MEMORY_SCOPE_AGENT);
}

// Hierarchical fence-free grid barrier: 16 cacheline-spaced sub-counters ->
// root -> 16 per-group release words. Relaxed atomics only (coherence point);
// explicit vmcnt drain before arrival is the release.
__device__ __forceinline__ void grid_barrier(unsigned int* bar, int nb,
                                             unsigned int ep) {
  __syncthreads();
  if (threadIdx.x == 0) {
    asm volatile("s_waitcnt vmcnt(0)" ::: "memory");  // drain data stores
    const int g = blockIdx.x & 15;
    const unsigned int gsz = (unsigned int)(nb >> 4);
    unsigned int old = __hip_atomic_fetch_add(&bar[g * 32], 1u,
                                              __ATOMIC_RELAXED,
                                              __HIP_MEMORY_SCOPE_AGENT);
    if (old == ep * gsz - 1u) {            // group leader
      unsigned int ro = __hip_atomic_fetch_add(&bar[512], 1u,
                                               __ATOMIC_RELAXED,
                                               __HIP_MEMORY_SCOPE_AGENT);
      if (ro == ep * 16u - 1u) {           // global last -> release all groups
#pragma unroll
        for (int i = 0; i < 16; i++)
          __hip_atomic_store(&bar[544 + i * 32], ep, __ATOMIC_RELAXED,
                             __HIP_MEMORY_SCOPE_AGENT);
      }
    }
    while (__hip_atomic_load(&bar[544 + g * 32], __ATOMIC_RELAXED,
                             __HIP_MEMORY_SCOPE_AGENT) < ep) {
      __builtin_amdgcn_s_sleep(2);
    }
  }
  asm volatile("" ::: "memory");
  __syncthreads();
}

// ---------------------------------------------------------------------------
// bf16 MFMA NT GEMM: C[m,n] = sum_k A[m,k]*B[n,k] (+bias[n]).
// ---------------------------------------------------------------------------
__global__ __launch_bounds__(256) void gemm_bf16_nt(
    const unsigned short* __restrict__ Am, const unsigned short* __restrict__ Bm,
    float* __restrict__ O, unsigned short* __restrict__ Obf,
    const float* __restrict__ bias, int M, int N, int K)
{
  __shared__ unsigned short sA[128 * 40];   // stride 40 -> bank-safe
  __shared__ unsigned short sB[128 * 40];
  const int tid = threadIdx.x;
  const int mt = blockIdx.y * 128, nt = blockIdx.x * 128;
  const int wave = tid >> 6, lane = tid & 63;
  const int wm = (wave & 1) * 64, wn = (wave >> 1) * 64;
  const int qd = lane >> 4, md = lane & 15;

  f32x4 acc[4][4];
#pragma unroll
  for (int i = 0; i < 4; i++)
#pragma unroll
    for (int j = 0; j < 4; j++) acc[i][j] = (f32x4){0.f, 0.f, 0.f, 0.f};

  for (int k0 = 0; k0 < K; k0 += 32) {
#pragma unroll
    for (int p = 0; p < 2; p++) {
      int idx = tid + p * 256;            // 0..511
      int r = idx >> 2, kq = (idx & 3) * 8;
      *(uint4*)&sA[r * 40 + kq] =
          *(const uint4*)&Am[(size_t)(mt + r) * K + k0 + kq];
      uint4 bv = make_uint4(0, 0, 0, 0);
      if (nt + r < N) bv = *(const uint4*)&Bm[(size_t)(nt + r) * K + k0 + kq];
      *(uint4*)&sB[r * 40 + kq] = bv;
    }
    __syncthreads();
    bf16x8 af[4], bfr[4];
#pragma unroll
    for (int i = 0; i < 4; i++) {
      af[i]  = *(const bf16x8*)&sA[(wm + i * 16 + md) * 40 + qd * 8];
      bfr[i] = *(const bf16x8*)&sB[(wn + i * 16 + md) * 40 + qd * 8];
    }
#pragma unroll
    for (int mi = 0; mi < 4; mi++)
#pragma unroll
      for (int ni = 0; ni < 4; ni++)
        acc[mi][ni] = __builtin_amdgcn_mfma_f32_16x16x32_bf16(
            af[mi], bfr[ni], acc[mi][ni], 0, 0, 0);
    __syncthreads();
  }

#pragma unroll
  for (int mi = 0; mi < 4; mi++)
#pragma unroll
    for (int ni = 0; ni < 4; ni++) {
      int gn = nt + wn + ni * 16 + md;
      if (gn >= N) continue;
      float bv = bias ? bias[gn] : 0.f;
#pragma unroll
      for (int reg = 0; reg < 4; reg++) {
        int gm = mt + wm + mi * 16 + qd * 4 + reg;
        float v = acc[mi][ni][reg] + bv;
        if (Obf) Obf[(size_t)gm * N + gn] = f2bf(v);
        else     O[(size_t)gm * N + gn] = v;
      }
    }
}

// ---------------------------------------------------------------------------
__global__ __launch_bounds__(256) void k_cvt_f4(
    const float4* __restrict__ in, ushort4* __restrict__ out, int n4)
{
  int i = blockIdx.x * 256 + threadIdx.x;
  if (i < n4) {
    float4 v = in[i];
    ushort4 o;
    o.x = f2bf(v.x); o.y = f2bf(v.y); o.z = f2bf(v.z); o.w = f2bf(v.w);
    out[i] = o;
  }
}

// Wcell[gate][h][k], gate 0=U(W_gy|W_sy), 1..4 = I,F,Cg,O (W_gs|W_ss)
__global__ __launch_bounds__(256) void k_build_wcell(
    const float* __restrict__ W_gy, const float* __restrict__ W_sy,
    const float* __restrict__ W_gs, const float* __restrict__ W_ss,
    unsigned short* __restrict__ Wc)
{
  int idx = blockIdx.x * 256 + threadIdx.x;
  if (idx >= 5 * H_ * KC_) return;
  int row = idx / KC_;
  int k = idx - row * KC_;
  int gt = row >> 9, h = row & (H_ - 1);
  float v;
  if (gt == 0)
    v = (k < D_) ? W_gy[(size_t)h * D_ + k] : W_sy[(size_t)h * H_ + (k - D_)];
  else {
    int r = (gt - 1) * H_ + h;
    v = (k < D_) ? W_gs[(size_t)r * D_ + k] : W_ss[(size_t)r * H_ + (k - D_)];
  }
  Wc[idx] = f2bf(v);
}

// ---------------------------------------------------------------------------
// Persistent decode kernel. Grid = 512 blocks (2/CU). Per step:
// A (512 energy tiles of 50t) -> bar -> B (512 softmax+g units) -> bar ->
// C (512 split-K cell units) -> bar -> D (32 reduce blocks; 480 idle blocks
// warm hE into L3 for next step's A) -> bar.
// ---------------------------------------------------------------------------
struct DecP {
  const unsigned short* hEbf;
  const unsigned short* hbbf;
  const unsigned short* Wcell;
  const unsigned short* W_sebf;
  const float* TY;
  const float* conv_w;
  const float* conv_b;
  const float* W_fe;
  const float* w_ee;
  const float* b_gy;
  const float* b_gs;
  const int* lengths;
  float* alpha;
  float* e;
  float* g;
  float* part;
  float* s0;
  float* s1;
  float* c;
  float* sE;
  unsigned short* u_all;
  unsigned int* bar;
  int nb;
};

__global__ __launch_bounds__(256) void k_decode(DecP p)
{
  const int bid = blockIdx.x;
  const int tid = threadIdx.x;
  const int nb = p.nb;

  // persistent (step-invariant) LDS
  __shared__ float s_wfeT[FC_ * A_];     // 32 KB
  __shared__ float s_cw[FC_ * K_];       // 6.4 KB
  __shared__ float s_wee[A_];            // 2 KB
  // per-phase scratch
  __shared__ float s_alpha[TT_ + K_ - 1];
  __shared__ float s_cf[800];            // A: conv feat (50*16); B: e-row (<=800)
  __shared__ float s_sE[A_];
  __shared__ float redA[256];
  __shared__ float redB[256];
  __shared__ float a_sh[256];
  __shared__ float sx[32 * 193];         // 24.7 KB
  __shared__ float sv[H_];

  for (int idx = tid; idx < FC_ * A_; idx += 256) {
    int f = idx >> 9, a = idx & (A_ - 1);
    s_wfeT[idx] = p.W_fe[a * FC_ + f];
  }
  for (int idx = tid; idx < FC_ * K_; idx += 256) s_cw[idx] = p.conv_w[idx];
  for (int idx = tid; idx < A_; idx += 256) s_wee[idx] = p.w_ee[idx];

  float* s_in = p.s0;
  float* s_out = p.s1;
  unsigned int ep = 0;

  for (int l = 0; l < L_; l++) {
    // ---------------- Phase A: attention energies (512 tiles, 1/block) -----
    {
      const int tile = bid;              // 512 tiles == nb
      const int b = tile >> 4;
      const int t0 = (tile & 15) * TT_;
      const int len = p.lengths[b];
      if (t0 < len) {                    // block-uniform
        for (int idx = tid; idx < TT_ + K_ - 1; idx += 256) {
          int t = t0 - (K_ / 2) + idx;
          s_alpha[idx] = (t >= 0 && t < T_) ? cload(&p.alpha[b * T_ + t]) : 0.f;
        }
        for (int idx = tid; idx < A_; idx += 256)
          s_sE[idx] = cload(&p.sE[b * A_ + idx]);
        __syncthreads();

        for (int idx = tid; idx < TT_ * FC_; idx += 256) {
          int tl = idx >> 4, f = idx & 15;
          float acc2 = p.conv_b[f];
          for (int k = 0; k < K_; k++)
            acc2 = fmaf(s_alpha[tl + k], s_cw[f * K_ + k], acc2);
          s_cf[tl * FC_ + f] = acc2;
        }
        __syncthreads();

        const int wave = tid >> 6, lane = tid & 63;
        for (int tl = wave; tl < TT_; tl += 4) {
          int t = t0 + tl;
          if (t >= len) continue;
          float cf[FC_];
#pragma unroll
          for (int f = 0; f < FC_; f++) cf[f] = s_cf[tl * FC_ + f];
          const unsigned short* hEp = p.hEbf + ((size_t)(b * T_ + t)) * A_;
          // preload all 4 hE words (4x MLP; was 1 in flight)
          unsigned int hp0 = *(const unsigned int*)&hEp[0 * 128 + lane * 2];
          unsigned int hp1 = *(const unsigned int*)&hEp[1 * 128 + lane * 2];
          unsigned int hp2 = *(const unsigned int*)&hEp[2 * 128 + lane * 2];
          unsigned int hp3 = *(const unsigned int*)&hEp[3 * 128 + lane * 2];
          unsigned int hps[4] = {hp0, hp1, hp2, hp3};
          float pt = 0.f;
#pragma unroll
          for (int j = 0; j < 4; j++) {
            int a0 = j * 128 + lane * 2;
            float F0 = 0.f, F1 = 0.f;
#pragma unroll
            for (int f = 0; f < FC_; f++) {
              float2 wf = *(const float2*)&s_wfeT[f * A_ + a0];
              F0 = fmaf(wf.x, cf[f], F0);
              F1 = fmaf(wf.y, cf[f], F1);
            }
            float v0 = fast_tanh(s_sE[a0] + bflo(hps[j]) + F0);
            float v1 = fast_tanh(s_sE[a0 + 1] + bfhi(hps[j]) + F1);
            pt = fmaf(s_wee[a0], v0, pt);
            pt = fmaf(s_wee[a0 + 1], v1, pt);
          }
#pragma unroll
          for (int off = 32; off > 0; off >>= 1) pt += __shfl_down(pt, off);
          if (lane == 0) cstore(&p.e[b * T_ + t], pt);
        }
        __syncthreads();
      }
    }
    grid_barrier(p.bar, nb, ++ep);

    // ---------------- Phase B: softmax + g (512 units of 64 dims) ----------
    for (int u = bid; u < 512; u += nb) {
      const int b = u & 31;
      const int d0 = (u >> 5) * 64;
      const int len = p.lengths[b];
      // stage e row to LDS once (s_cf: 800 floats >= len<=800)
      for (int t = tid; t < len; t += 256) s_cf[t] = cload(&p.e[b * T_ + t]);
      __syncthreads();
      float m = -3.0e38f;
      for (int t = tid; t < len; t += 256) m = fmaxf(m, s_cf[t]);
      redA[tid] = m;
      __syncthreads();
      for (int s2 = 128; s2 > 0; s2 >>= 1) {
        if (tid < s2) redA[tid] = fmaxf(redA[tid], redA[tid + s2]);
        __syncthreads();
      }
      m = redA[0];
      __syncthreads();
      float zs = 0.f;
      for (int t = tid; t < len; t += 256) zs += __expf(s_cf[t] - m);
      redA[tid] = zs;
      __syncthreads();
      for (int s2 = 128; s2 > 0; s2 >>= 1) {
        if (tid < s2) redA[tid] += redA[tid + s2];
        __syncthreads();
      }
      const float invZ = 1.f / redA[0];
      __syncthreads();

      const int dloc = (tid & 31) * 2, tph = tid >> 5;   // 8 t-phases x 32 lanes
      float g0 = 0.f, g1 = 0.f;
      const unsigned short* hbbase =
          p.hbbf + (size_t)b * T_ * D_ + d0 + dloc;
      for (int tb = 0; tb < len; tb += 256) {
        int t = tb + tid;
        float av = (t < len) ? __expf(s_cf[t] - m) * invZ : 0.f;
        a_sh[tid] = av;
        __syncthreads();
        if (d0 == 0 && t < len) cstore(&p.alpha[b * T_ + t], av);
        int cnt = min(256, len - tb);
        // 1-ahead software pipeline on the hb stream (2x MLP)
        int tt = tph;
        unsigned int hpn = 0;
        if (tt < cnt)
          hpn = *(const unsigned int*)&hbbase[(size_t)(tb + tt) * D_];
        while (tt < cnt) {
          unsigned int hp = hpn;
          int ttn = tt + 8;
          if (ttn < cnt)
            hpn = *(const unsigned int*)&hbbase[(size_t)(tb + ttn) * D_];
          float av2 = a_sh[tt];
          g0 = fmaf(av2, bflo(hp), g0);
          g1 = fmaf(av2, bfhi(hp), g1);
          tt = ttn;
        }
        __syncthreads();
      }
      redA[tid] = g0;
      redB[tid] = g1;
      __syncthreads();
      if (tid < 32) {
        float r0 = 0.f, r1 = 0.f;
#pragma unroll
        for (int k2 = 0; k2 < 8; k2++) {
          r0 += redA[tid + 32 * k2];
          r1 += redB[tid + 32 * k2];
        }
        cstore(&p.g[b * D_ + d0 + 2 * tid],     r0);
        cstore(&p.g[b * D_ + d0 + 2 * tid + 1], r1);
      }
      __syncthreads();
    }
    grid_barrier(p.bar, nb, ++ep);

    // ---------------- Phase C: cell partials (split-K x8) ----------------
    for (int u = bid; u < 512; u += nb) {
      const int ks = u >> 6;
      const int xb = u & 63;
      const int k0 = ks * 192;
      for (int i = tid; i < 32 * 192; i += 256) {
        int bb = i / 192, dd = i - bb * 192;
        int k = k0 + dd;
        sx[bb * 193 + dd] = (k < D_) ? cload(&p.g[bb * D_ + k])
                                     : cload(&s_in[bb * H_ + (k - D_)]);
      }
      __syncthreads();
      const int gid = xb * 256 + tid;
      const int b = gid & 31, h = gid >> 5;
      const float* xp = &sx[b * 193];
      float acc[5] = {0.f, 0.f, 0.f, 0.f, 0.f};
      const uint4* w[5];
#pragma unroll
      for (int gt = 0; gt < 5; gt++)
        w[gt] = (const uint4*)(p.Wcell + ((size_t)(gt * H_ + h)) * KC_ + k0);
#pragma unroll 4
      for (int i = 0; i < 24; i++) {
        uint4 uu[5];
#pragma unroll
        for (int gt = 0; gt < 5; gt++) uu[gt] = w[gt][i];
        float xv[8];
#pragma unroll
        for (int e2 = 0; e2 < 8; e2++) xv[e2] = xp[i * 8 + e2];
#pragma unroll
        for (int gt = 0; gt < 5; gt++) {
          acc[gt] = fmaf(bflo(uu[gt].x), xv[0], acc[gt]);
          acc[gt] = fmaf(bfhi(uu[gt].x), xv[1], acc[gt]);
          acc[gt] = fmaf(bflo(uu[gt].y), xv[2], acc[gt]);
          acc[gt] = fmaf(bfhi(uu[gt].y), xv[3], acc[gt]);
          acc[gt] = fmaf(bflo(uu[gt].z), xv[4], acc[gt]);
          acc[gt] = fmaf(bfhi(uu[gt].z), xv[5], acc[gt]);
          acc[gt] = fmaf(bflo(uu[gt].w), xv[6], acc[gt]);
          acc[gt] = fmaf(bfhi(uu[gt].w), xv[7], acc[gt]);
        }
      }
      // part layout: [plane][b*512 + h] -> D reads coalesced
#pragma unroll
      for (int gt = 0; gt < 5; gt++)
        cstore(&p.part[(size_t)(ks * 5 + gt) * 16384 + b * 512 + h], acc[gt]);
      __syncthreads();   // protect sx before next unit
    }
    grid_barrier(p.bar, nb, ++ep);

    // ---------------- Phase D: reduce + state + sE; idle blocks warm hE ----
    if (bid < 32) {
      const int b = bid;
      const float* ty = p.TY + ((size_t)b * L_ + l) * (4 * H_);
      for (int h = tid; h < H_; h += 256) {
        float s5[5] = {0.f, 0.f, 0.f, 0.f, 0.f};
#pragma unroll
        for (int ks = 0; ks < 8; ks++)
#pragma unroll
          for (int gt = 0; gt < 5; gt++)
            s5[gt] += cload(&p.part[(size_t)(ks * 5 + gt) * 16384 + b * 512 + h]);
        float uv = fast_tanh(s5[0] + p.b_gy[h]);
        float iv = s5[1] + ty[h] + p.b_gs[h];
        float fv = s5[2] + ty[h + H_] + p.b_gs[h + H_];
        float cg2 = s5[3] + ty[h + 2 * H_] + p.b_gs[h + 2 * H_];
        float ov = s5[4] + ty[h + 3 * H_] + p.b_gs[h + 3 * H_];
        float cn = fast_sig(fv) * p.c[b * H_ + h] + fast_sig(iv) * fast_tanh(cg2);
        p.c[b * H_ + h] = cn;                       // block-local: plain
        float sn = fast_sig(ov) * fast_tanh(cn);
        cstore(&s_out[b * H_ + h], sn);
        sv[h] = sn;
        p.u_all[((size_t)b * L_ + l) * H_ + h] = f2bf(uv);  // read post-kernel
      }
      __syncthreads();
      for (int a = tid; a < A_; a += 256) {
        const uint4* row = (const uint4*)(p.W_sebf + (size_t)a * H_);
        float acc = 0.f;
#pragma unroll 8
        for (int i = 0; i < 64; i++) {
          uint4 ww = row[i];
          const float* xp2 = &sv[i * 8];
          acc = fmaf(bflo(ww.x), xp2[0], acc);
          acc = fmaf(bfhi(ww.x), xp2[1], acc);
          acc = fmaf(bflo(ww.y), xp2[2], acc);
          acc = fmaf(bfhi(ww.y), xp2[3], acc);
          acc = fmaf(bflo(ww.z), xp2[4], acc);
          acc = fmaf(bfhi(ww.z), xp2[5], acc);
          acc = fmaf(bflo(ww.w), xp2[6], acc);
          acc = fmaf(bfhi(ww.w), xp2[7], acc);
        }
        cstore(&p.sE[b * A_ + a], acc);
      }
    } else if (l + 1 < L_) {
      // 480 idle blocks: stream-touch hE so next step's phase A hits L3,
      // overlapping the HBM fetch with D's serial work.
      const uint4* src = (const uint4*)p.hEbf;
      const size_t n16 = (size_t)B_ * T_ * A_ * 2 / 16;   // 1,638,400
      size_t i = (size_t)(bid - 32) * 256 + tid;
      for (; i < n16; i += (size_t)480 * 256) {
        uint4 v = src[i];
        asm volatile("" :: "v"(v.x), "v"(v.y), "v"(v.z), "v"(v.w));
      }
    }
    grid_barrier(p.bar, nb, ++ep);

    float* tmp = s_in; s_in = s_out; s_out = tmp;
  }
}

// ---------------------------------------------------------------------------
extern "C" void kernel_launch(void* const* d_in, const int* in_sizes, int n_in,
                              void* d_out, int out_size, void* d_ws, size_t ws_size,
                              hipStream_t stream)
{
  const float* hbatch  = (const float*)d_in[0];
  const int*   lengths = (const int*)d_in[1];
  const float* targets = (const float*)d_in[2];
  const float* W_sy = (const float*)d_in[3];
  const float* W_gy = (const float*)d_in[4];
  const float* b_gy = (const float*)d_in[5];
  const float* W_yy = (const float*)d_in[6];
  const float* b_yy = (const float*)d_in[7];
  const float* W_ys = (const float*)d_in[8];
  const float* W_ss = (const float*)d_in[9];
  const float* W_gs = (const float*)d_in[10];
  const float* b_gs = (const float*)d_in[11];
  const float* W_se = (const float*)d_in[12];
  const float* W_he = (const float*)d_in[13];
  const float* W_fe = (const float*)d_in[14];
  const float* conv_w = (const float*)d_in[15];
  const float* conv_b = (const float*)d_in[16];
  const float* w_ee   = (const float*)d_in[17];
  float* out = (float*)d_out;

  char* ws = (char*)d_ws;
  size_t off = 0;
  auto alloc = [&](size_t bytes) -> void* {
    void* p = ws + off;
    off += (bytes + 255) & ~(size_t)255;
    return p;
  };
  unsigned short* hEbf   = (unsigned short*)alloc((size_t)B_ * T_ * A_ * 2);   // 26.2 MB
  unsigned short* hbbf   = (unsigned short*)alloc((size_t)B_ * T_ * D_ * 2);   // 52.4 MB
  unsigned short* Wcell  = (unsigned short*)alloc((size_t)5 * H_ * KC_ * 2);   // 7.9 MB
  unsigned short* Wyybf  = (unsigned short*)alloc((size_t)C_ * H_ * 2);        // 4.1 MB
  unsigned short* W_hebf = (unsigned short*)alloc((size_t)A_ * D_ * 2);        // 1.0 MB
  unsigned short* W_sebf = (unsigned short*)alloc((size_t)A_ * H_ * 2);        // 0.5 MB
  unsigned short* u_all  = (unsigned short*)alloc((size_t)B_ * L_ * H_ * 2);   // 2.0 MB
  float* TY    = (float*)alloc((size_t)B_ * L_ * 4 * H_ * 4);                  // 15.7 MB
  float* part  = (float*)alloc((size_t)8 * 5 * 16384 * 4);                     // 2.6 MB
  float* alpha = (float*)alloc((size_t)B_ * T_ * 4);
  float* e     = (float*)alloc((size_t)B_ * T_ * 4);
  float* g     = (float*)alloc((size_t)B_ * D_ * 4);
  float* s0    = (float*)alloc((size_t)B_ * H_ * 4);
  float* s1    = (float*)alloc((size_t)B_ * H_ * 4);
  float* c     = (float*)alloc((size_t)B_ * H_ * 4);
  float* sE    = (float*)alloc((size_t)B_ * A_ * 4);
  unsigned int* bar = (unsigned int*)alloc(8192);  // hierarchical barrier state

  // Precompute-only scratch aliases (dead after TY GEMM, stream-ordered):
  unsigned short* targetsbf = hEbf;   // 15.4 MB <= 26.2 MB
  unsigned short* W_ysbf    = hbbf;   // 16.4 MB <= 52.4 MB

  (void)hipMemsetAsync(alpha, 0, (size_t)B_ * T_ * 4, stream);
  (void)hipMemsetAsync(s0, 0, (size_t)B_ * H_ * 4, stream);
  (void)hipMemsetAsync(c, 0, (size_t)B_ * H_ * 4, stream);
  (void)hipMemsetAsync(sE, 0, (size_t)B_ * A_ * 4, stream);
  (void)hipMemsetAsync(bar, 0, 8192, stream);

  // ---- precompute ----
  {
    int n4t = B_ * L_ * C_ / 4;
    k_cvt_f4<<<(n4t + 255) / 256, 256, 0, stream>>>((const float4*)targets,
                                                    (ushort4*)targetsbf, n4t);
    int n4w = 4 * H_ * C_ / 4;
    k_cvt_f4<<<(n4w + 255) / 256, 256, 0, stream>>>((const float4*)W_ys,
                                                    (ushort4*)W_ysbf, n4w);
    gemm_bf16_nt<<<dim3(2048 / 128, 1920 / 128), 256, 0, stream>>>(
        targetsbf, W_ysbf, TY, nullptr, nullptr, 1920, 2048, 4000);

    int n4h = B_ * T_ * D_ / 4;
    k_cvt_f4<<<(n4h + 255) / 256, 256, 0, stream>>>((const float4*)hbatch,
                                                    (ushort4*)hbbf, n4h);
    int n4e = A_ * D_ / 4;
    k_cvt_f4<<<(n4e + 255) / 256, 256, 0, stream>>>((const float4*)W_he,
                                                    (ushort4*)W_hebf, n4e);
    gemm_bf16_nt<<<dim3(A_ / 128, (B_ * T_) / 128), 256, 0, stream>>>(
        hbbf, W_hebf, nullptr, hEbf, nullptr, B_ * T_, A_, D_);

    int n4y = C_ * H_ / 4;
    k_cvt_f4<<<(n4y + 255) / 256, 256, 0, stream>>>((const float4*)W_yy,
                                                    (ushort4*)Wyybf, n4y);
    int n4s = A_ * H_ / 4;
    k_cvt_f4<<<(n4s + 255) / 256, 256, 0, stream>>>((const float4*)W_se,
                                                    (ushort4*)W_sebf, n4s);
    int nw = 5 * H_ * KC_;
    k_build_wcell<<<(nw + 255) / 256, 256, 0, stream>>>(W_gy, W_sy, W_gs, W_ss,
                                                        Wcell);
  }

  // ---- persistent decode: 512 blocks hard-coded (2/CU; no occupancy query
  // here — it fails under graph capture, r6 lesson) ----
  DecP p;
  p.hEbf = hEbf; p.hbbf = hbbf; p.Wcell = Wcell; p.W_sebf = W_sebf;
  p.TY = TY; p.conv_w = conv_w; p.conv_b = conv_b; p.W_fe = W_fe;
  p.w_ee = w_ee; p.b_gy = b_gy; p.b_gs = b_gs; p.lengths = lengths;
  p.alpha = alpha; p.e = e; p.g = g; p.part = part;
  p.s0 = s0; p.s1 = s1; p.c = c; p.sE = sE; p.u_all = u_all;
  p.bar = bar; p.nb = NB_;
  k_decode<<<dim3(NB_), dim3(256), 0, stream>>>(p);

  // ---- final: out[b,l,:] = u_all @ W_yy.T + b_yy  (bf16 MFMA) ----
  gemm_bf16_nt<<<dim3((C_ + 127) / 128, 1920 / 128), 256, 0, stream>>>(
      u_all, Wyybf, out, nullptr, b_yy, 1920, C_, H_);
}